// Round 10
// baseline (663.631 us; speedup 1.0000x reference)
//
#include <hip/hip_runtime.h>
#include <math.h>

// Problem constants (fixed by reference setup_inputs)
#define B   8
#define C   64
#define HH  192
#define WWD 192
#define P   (HH*WWD)     // 36864
#define NC  2
#define NS  8
#define PP  (194*194)    // padded space map (1-px zero halo), 37636

// Workspace layout (float offsets)
#define OFF_SPACE 0                    // 128 maps * PP = 4817408 (zero-padded)
// Wt, gmap, WsT REUSE the spp region (dead after k_R2).
#define OFF_WT    0                    // 8*576*64 = 294912 transposed Wxs
#define OFF_GM    294912               // 8*2*P = 589824 combined attention maps
#define OFF_WST   884736               // 64*9*64 = 36864 transposed Wsing [ci][t][oc]
#define OFF_SPART 4817408              // 128*144 per-block S partials
#define OFF_R     4835840              // 8*16*64*9 = 73728 correlations (zeroed; k_R2 accumulates)
#define OFF_TOK2  4909568              // 8*2*64 = 1024 (atomic accumulated, needs zero)
#define OFF_U     4910592              // 8*64*2*9 = 9216 collapsed conv weights
#define OFF_STP   4919808              // 2*64*288 BN partial sums ([slot][oc] major)
#define OFF_SCALE 4956672              // 64
#define OFF_SHIFT 4956736              // 64
#define WS_FLOATS 4956800              // ~19.8 MB total

typedef __attribute__((ext_vector_type(8))) short bfrag;   // 8 bf16 (4 VGPRs)
typedef __attribute__((ext_vector_type(4))) float ffrag;   // 4 f32 acc

__device__ __forceinline__ float sigm(float x) { return 1.0f / (1.0f + expf(-x)); }

// K1: space maps (sigmoid + 1->7 ch 3x3 conv + sigmoid) into zero-padded layout,
// plus per-(map,ch) per-block partial sums (NO global atomics).
__global__ void k_space(const float* __restrict__ cs, const float* __restrict__ Wc,
                        float* __restrict__ spp, float* __restrict__ Spart) {
    int m = blockIdx.y;                       // m = b*2 + c
    int bx = blockIdx.x;
    int p = bx * 256 + threadIdx.x;           // 144*256 == P exactly
    int h = p / WWD, w = p - (p / WWD) * WWD;
    float cp[9];
    #pragma unroll
    for (int ky = 0; ky < 3; ky++)
        #pragma unroll
        for (int kx = 0; kx < 3; kx++) {
            int hh = h + ky - 1, ww = w + kx - 1;
            float v = 0.f;  // zero-pad AFTER sigmoid (conv pads class_prob with 0)
            if ((unsigned)hh < HH && (unsigned)ww < WWD)
                v = sigm(cs[m * P + hh * WWD + ww]);
            cp[ky * 3 + kx] = v;
        }
    float ch[8];
    ch[0] = cp[4];
    #pragma unroll
    for (int j = 0; j < 7; j++) {
        float a = 0.f;
        #pragma unroll
        for (int k = 0; k < 9; k++) a += Wc[j * 9 + k] * cp[k];
        ch[j + 1] = sigm(a);
    }
    #pragma unroll
    for (int q = 0; q < 8; q++)
        spp[(m * 8 + q) * PP + (h + 1) * 194 + (w + 1)] = ch[q];
    // per-wave shfl reduce -> LDS -> per-block partial (no atomics)
    __shared__ float red[4][8];
    int lane = threadIdx.x & 63, wave = threadIdx.x >> 6;
    #pragma unroll
    for (int q = 0; q < 8; q++) {
        float v = ch[q];
        for (int off = 32; off > 0; off >>= 1) v += __shfl_down(v, off);
        if (lane == 0) red[wave][q] = v;
    }
    __syncthreads();
    if (threadIdx.x < 8) {
        int q = threadIdx.x;
        Spart[(m * 8 + q) * 144 + bx] = red[0][q] + red[1][q] + red[2][q] + red[3][q];
    }
}

// ---- k_R2: MFMA rewrite ---------------------------------------------------
// R[b,sc,i,t=ty*3+tx] = sum_{h,w} x_i(h,w) * gpad_sc(h+2-ty, w+2-tx)
// MFMA 16x16x32 bf16: M=i (wave owns 16 ch), N=sc (16 maps), K=w along one
// image row (192 = 6 K-steps). Taps: 3 row offsets (dy) x 3 col shifts (dx)
// built from LDS-staged padded g rows; dx shifts via alignbit on aligned reads.
// Precision: hi/lo bf16 split (xh*gh + xh*gl + xl*gh) ~ 2^-16 relative.
// Block = (b, 2-row chunk): stage 4 padded g rows x 16 maps (bf16 hi+lo planes,
// 51.5KB LDS -> 3 blocks/CU), 4 waves = 4 i-groups. acc = 9 taps x f32x4 = 36
// VGPR -- the accumulator pressure that killed 4 VALU restructures lives in
// MFMA fragments now. x read ONCE (75MB total vs 1.2GB). atomicAdd partials
// into R (96 h-chunks per element; R pre-zeroed).
#define GH_MAP 804   // ushorts per map slot (4 rows x 200 + pad; stride words%32=18 -> spread)
#define GH_ROW 200

__device__ __forceinline__ void bfpair(float v0, float v1, unsigned& h, unsigned& lo) {
    unsigned u0 = __float_as_uint(v0), u1 = __float_as_uint(v1);
    float r0 = v0 - __uint_as_float(u0 & 0xffff0000u);
    float r1 = v1 - __uint_as_float(u1 & 0xffff0000u);
    h  = (u0 >> 16) | (u1 & 0xffff0000u);
    lo = (__float_as_uint(r0) >> 16) | (__float_as_uint(r1) & 0xffff0000u);
}

__device__ __forceinline__ bfrag mkfrag(unsigned a, unsigned b, unsigned c, unsigned d) {
    unsigned q[4] = {a, b, c, d};
    bfrag f;
    __builtin_memcpy(&f, q, 16);
    return f;
}

__launch_bounds__(256, 3)
__global__ void k_R2(const float* __restrict__ x, const float* __restrict__ spp,
                     float* __restrict__ R) {
    int hc = blockIdx.x;          // 0..95 : 2-row chunk
    int b  = blockIdx.y;
    int tid = threadIdx.x;
    int wv = tid >> 6, l = tid & 63;
    int h0 = hc * 2;

    __shared__ unsigned short gh[16 * GH_MAP], gl[16 * GH_MAP];

    // stage padded g rows h0..h0+3 of all 16 maps, split into bf16 hi/lo planes
    for (int idx = tid; idx < 16 * 4 * 194; idx += 256) {
        int n = idx / 776;
        int rem = idx - n * 776;
        int r = rem / 194, col = rem - r * 194;
        const float* sp = spp + ((b * NC + (n & 1)) * NS + (n >> 1)) * PP;
        float v = sp[(h0 + r) * 194 + col];
        unsigned u = __float_as_uint(v);
        float res = v - __uint_as_float(u & 0xffff0000u);
        gh[n * GH_MAP + r * GH_ROW + col] = (unsigned short)(u >> 16);
        gl[n * GH_MAP + r * GH_ROW + col] = (unsigned short)(__float_as_uint(res) >> 16);
    }
    __syncthreads();

    ffrag acc[3][3];
    #pragma unroll
    for (int a = 0; a < 3; a++)
        #pragma unroll
        for (int d = 0; d < 3; d++) acc[a][d] = (ffrag){0.f, 0.f, 0.f, 0.f};

    int i0 = wv * 16;
    int g8 = (l >> 4) * 8;                          // k-offset of this lane group
    const float* xbase = x + (size_t)((b * C + i0 + (l & 15)) * HH) * WWD;
    const unsigned short* ghn = gh + (l & 15) * GH_MAP + g8;
    const unsigned short* gln = gl + (l & 15) * GH_MAP + g8;

    for (int lr = 0; lr < 2; lr++) {
        const float* xr = xbase + (h0 + lr) * WWD + g8;
        #pragma unroll
        for (int ks = 0; ks < 6; ks++) {
            float4 a0 = *(const float4*)(xr + ks * 32);
            float4 a1 = *(const float4*)(xr + ks * 32 + 4);
            unsigned ah0, ah1, ah2, ah3, al0, al1, al2, al3;
            bfpair(a0.x, a0.y, ah0, al0);
            bfpair(a0.z, a0.w, ah1, al1);
            bfpair(a1.x, a1.y, ah2, al2);
            bfpair(a1.z, a1.w, ah3, al3);
            bfrag ah = mkfrag(ah0, ah1, ah2, ah3);
            bfrag al = mkfrag(al0, al1, al2, al3);
            #pragma unroll
            for (int dy = 0; dy < 3; dy++) {
                const unsigned short* ph = ghn + (lr + dy) * GH_ROW + ks * 32;
                const unsigned short* pl = gln + (lr + dy) * GH_ROW + ks * 32;
                unsigned uh[5], ul[5];
                *(uint2*)&uh[0] = *(const uint2*)(ph);
                *(uint2*)&uh[2] = *(const uint2*)(ph + 4);
                uh[4] = *(const unsigned*)(ph + 8);
                *(uint2*)&ul[0] = *(const uint2*)(pl);
                *(uint2*)&ul[2] = *(const uint2*)(pl + 4);
                ul[4] = *(const unsigned*)(pl + 8);
                // dx=0: els0..7 ; dx=1: els1..8 (alignbit) ; dx=2: els2..9
                bfrag bh0 = mkfrag(uh[0], uh[1], uh[2], uh[3]);
                bfrag bh1 = mkfrag((uh[0] >> 16) | (uh[1] << 16), (uh[1] >> 16) | (uh[2] << 16),
                                   (uh[2] >> 16) | (uh[3] << 16), (uh[3] >> 16) | (uh[4] << 16));
                bfrag bh2 = mkfrag(uh[1], uh[2], uh[3], uh[4]);
                bfrag bl0 = mkfrag(ul[0], ul[1], ul[2], ul[3]);
                bfrag bl1 = mkfrag((ul[0] >> 16) | (ul[1] << 16), (ul[1] >> 16) | (ul[2] << 16),
                                   (ul[2] >> 16) | (ul[3] << 16), (ul[3] >> 16) | (ul[4] << 16));
                bfrag bl2 = mkfrag(ul[1], ul[2], ul[3], ul[4]);
                acc[dy][0] = __builtin_amdgcn_mfma_f32_16x16x32_bf16(ah, bh0, acc[dy][0], 0, 0, 0);
                acc[dy][0] = __builtin_amdgcn_mfma_f32_16x16x32_bf16(ah, bl0, acc[dy][0], 0, 0, 0);
                acc[dy][0] = __builtin_amdgcn_mfma_f32_16x16x32_bf16(al, bh0, acc[dy][0], 0, 0, 0);
                acc[dy][1] = __builtin_amdgcn_mfma_f32_16x16x32_bf16(ah, bh1, acc[dy][1], 0, 0, 0);
                acc[dy][1] = __builtin_amdgcn_mfma_f32_16x16x32_bf16(ah, bl1, acc[dy][1], 0, 0, 0);
                acc[dy][1] = __builtin_amdgcn_mfma_f32_16x16x32_bf16(al, bh1, acc[dy][1], 0, 0, 0);
                acc[dy][2] = __builtin_amdgcn_mfma_f32_16x16x32_bf16(ah, bh2, acc[dy][2], 0, 0, 0);
                acc[dy][2] = __builtin_amdgcn_mfma_f32_16x16x32_bf16(ah, bl2, acc[dy][2], 0, 0, 0);
                acc[dy][2] = __builtin_amdgcn_mfma_f32_16x16x32_bf16(al, bh2, acc[dy][2], 0, 0, 0);
            }
        }
    }

    // D lane map (16x16x32): col = l&15 (=sc), row = (l>>4)*4 + reg (=i within group).
    // tap (dy,dx) corresponds to t = 8 - (dy*3+dx)  [ty=2-dy, tx=2-dx].
    #pragma unroll
    for (int dy = 0; dy < 3; dy++)
        #pragma unroll
        for (int dx = 0; dx < 3; dx++) {
            int t = 8 - (dy * 3 + dx);
            #pragma unroll
            for (int rg = 0; rg < 4; rg++) {
                int i = i0 + (l >> 4) * 4 + rg;
                atomicAdd(&R[((b * 16 + (l & 15)) * 64 + i) * 9 + t], acc[dy][dx][rg]);
            }
        }
}
// ---------------------------------------------------------------------------

// K2b: BOTH weight transposes in one launch (flat grid, branch on block range).
__global__ void k_wtb(const float* __restrict__ Wxs, const float* __restrict__ Ws,
                      float* __restrict__ Wt, float* __restrict__ WsT) {
    int blk = blockIdx.x;
    if (blk < 1152) {
        int o = blk * 256 + threadIdx.x;          // output-coalesced
        int d = o & 63, r = o >> 6;               // r = s*576+t
        int s = r / 576, t = r - s * 576;
        Wt[o] = Wxs[(s * 64 + d) * 576 + t];
    } else {
        int o = (blk - 1152) * 256 + threadIdx.x; // output-coalesced
        int ci = o / 576, q = o - ci * 576;
        int t = q >> 6, oc = q & 63;
        WsT[o] = Ws[(oc * 64 + ci) * 9 + t];
    }
}

// K2c: combined attention map gmap[b][cl][p] = sum_s Wcomb[s]*Wcval[s]*sigm(sigm(cs)*Wattn[s])
__global__ void k_g(const float* __restrict__ cs, const float* __restrict__ Wcval,
                    const float* __restrict__ Wattn, const float* __restrict__ Wcomb,
                    float* __restrict__ gmap) {
    int m = blockIdx.y;                       // b*2 + cl
    int p = blockIdx.x * 256 + threadIdx.x;   // 144*256 == P
    float wa[8], wt[8];
    #pragma unroll
    for (int s = 0; s < 8; s++) { wa[s] = Wcomb[s] * Wcval[s]; wt[s] = Wattn[s]; }
    float cp = sigm(cs[m * P + p]);
    float a = 0.f;
    #pragma unroll
    for (int s = 0; s < 8; s++) a += wa[s] * sigm(cp * wt[s]);
    gmap[m * P + p] = a;
}

// K3: tok2[b,c,d] = sum_s Wcs[s]/S[b,c,s] * sum_t Wt[s][t][d] * R[b,s,c,t]
__global__ void k_tok2(const float* __restrict__ Wt, const float* __restrict__ Wcs,
                       const float* __restrict__ R, const float* __restrict__ Spart,
                       float* __restrict__ tok2) {
    int bc = blockIdx.x, s = blockIdx.y, tz = blockIdx.z;
    int d = threadIdx.x;
    const float* spp = Spart + (bc * 8 + s) * 144;
    float sv = 0.f;
    for (int k = d; k < 144; k += 64) sv += spp[k];
    #pragma unroll
    for (int msk = 32; msk >= 1; msk >>= 1) sv += __shfl_xor(sv, msk);

    const float* Rp = R + ((bc & 1) + ((bc >> 1) * 16 + s * 2)) * 576;
    const float* Wp = Wt + s * 576 * 64 + d;
    float a = 0.f;
    int t0 = tz * 144;
    #pragma unroll 8
    for (int t = t0; t < t0 + 144; t++) a += Wp[t * 64] * Rp[t];
    float val = a * Wcs[s] / sv;
    atomicAdd(&tok2[bc * C + d], val);
}

// K4: U[b][oc][m][t] = sum_ci Ws[oc,ci,t]*tok2[b,m,ci], via transposed WsT[ci][t][oc].
__global__ void k_U(const float* __restrict__ WsT, const float* __restrict__ tok2,
                    float* __restrict__ U) {
    int b = blockIdx.x, m = blockIdx.y;
    int tid = threadIdx.x;                 // 0..575
    int oc = tid & 63, t = tid >> 6;
    __shared__ float tok[64];
    if (tid < 64) tok[tid] = tok2[(b * NC + m) * C + tid];
    __syncthreads();
    float a = 0.f;
    #pragma unroll 8
    for (int ci = 0; ci < C; ci++) a += WsT[ci * 576 + tid] * tok[ci];
    U[((b * C + oc) * 2 + m) * 9 + t] = a;
}

// Shared staging: g0/g1 34x34 halo tiles from precomputed gmap (pure coalesced copy).
__device__ __forceinline__ void stage_g(const float* __restrict__ gmap, int b, int ty0, int tx0,
                                        float* h0, float* h1) {
    const float* g0p = gmap + (b * NC + 0) * P;
    const float* g1p = gmap + (b * NC + 1) * P;
    for (int idx = threadIdx.x; idx < 34 * 34; idx += 256) {
        int i = idx / 34, j = idx - (idx / 34) * 34;
        int gy = ty0 - 1 + i, gx = tx0 - 1 + j;
        float a0 = 0.f, a1 = 0.f;
        if ((unsigned)gy < HH && (unsigned)gx < WWD) {
            int p = gy * WWD + gx;
            a0 = g0p[p]; a1 = g1p[p];
        }
        h0[i * 35 + j] = a0; h1[i * 35 + j] = a1;
    }
}

// K5: BN partials. Stage tile ONCE, loop 4 ocg groups over it. Grid (36, 2, 8).
__launch_bounds__(256)
__global__ void k_cs(const float* __restrict__ gmap, const float* __restrict__ U,
                     float* __restrict__ STp) {
    int tile = blockIdx.x, og2 = blockIdx.y, b = blockIdx.z;
    int ty0 = (tile / 6) * 32, tx0 = (tile % 6) * 32;
    __shared__ float h0[34 * 35], h1[34 * 35];
    stage_g(gmap, b, ty0, tx0, h0, h1);
    __syncthreads();

    int w = __builtin_amdgcn_readfirstlane(threadIdx.x >> 6);
    int lane = threadIdx.x & 63;
    for (int g4 = 0; g4 < 4; g4++) {
        int oc0 = (og2 * 4 + g4) * 8 + w * 2;
        float u0[2][9], u1[2][9];
        #pragma unroll
        for (int j = 0; j < 2; j++) {
            const float* up = U + ((b * C + oc0 + j) * 2) * 9;
            #pragma unroll
            for (int t = 0; t < 9; t++) { u0[j][t] = up[t]; u1[j][t] = up[9 + t]; }
        }
        float s1[2] = {0.f, 0.f}, s2[2] = {0.f, 0.f};
        for (int it = 0; it < 4; it++) {
            int row = it * 8 + (lane >> 3);
            int c0 = (lane & 7) * 4;
            float g0v[3][6], g1v[3][6];
            #pragma unroll
            for (int dy = 0; dy < 3; dy++)
                #pragma unroll
                for (int dx = 0; dx < 6; dx++) {
                    g0v[dy][dx] = h0[(row + dy) * 35 + c0 + dx];
                    g1v[dy][dx] = h1[(row + dy) * 35 + c0 + dx];
                }
            #pragma unroll
            for (int j = 0; j < 2; j++)
                #pragma unroll
                for (int px = 0; px < 4; px++) {
                    float y = 0.f;
                    #pragma unroll
                    for (int ky = 0; ky < 3; ky++)
                        #pragma unroll
                        for (int kx = 0; kx < 3; kx++) {
                            y += u0[j][ky * 3 + kx] * g0v[ky][px + kx];
                            y += u1[j][ky * 3 + kx] * g1v[ky][px + kx];
                        }
                    s1[j] += y; s2[j] += y * y;
                }
        }
        #pragma unroll
        for (int j = 0; j < 2; j++) {
            float a = s1[j], q = s2[j];
            for (int off = 32; off > 0; off >>= 1) { a += __shfl_down(a, off); q += __shfl_down(q, off); }
            if (lane == 0) {
                int slot = b * 36 + tile;
                STp[slot * 64 + (oc0 + j)] = a;
                STp[288 * 64 + slot * 64 + (oc0 + j)] = q;
            }
        }
    }
}

// K6: finalize BN scale/shift. 256 threads (4-way k-split + LDS combine).
__global__ void k_bnfin(const float* __restrict__ STp, const float* __restrict__ gamma,
                        const float* __restrict__ beta, float* __restrict__ scale,
                        float* __restrict__ shift) {
    int oc = threadIdx.x & 63, q = threadIdx.x >> 6;
    double s = 0.0, s2 = 0.0;
    for (int k = q * 72; k < q * 72 + 72; k++) {
        s  += (double)STp[k * 64 + oc];
        s2 += (double)STp[288 * 64 + k * 64 + oc];
    }
    __shared__ double ls[4][64], ls2[4][64];
    ls[q][oc] = s; ls2[q][oc] = s2;
    __syncthreads();
    if (threadIdx.x < 64) {
        double S  = ls[0][oc] + ls[1][oc] + ls[2][oc] + ls[3][oc];
        double S2 = ls2[0][oc] + ls2[1][oc] + ls2[2][oc] + ls2[3][oc];
        double n = (double)(B * P);
        double mean = S / n;
        double var = S2 / n - mean * mean;
        float sc = gamma[oc] * rsqrtf((float)var + 1e-5f);
        scale[oc] = sc;
        shift[oc] = beta[oc] - (float)mean * sc;
    }
}

// K7: out = x + relu(y*scale+shift). Stage tile once, loop 4 ocg groups.
__launch_bounds__(256)
__global__ void k_fin2(const float* __restrict__ gmap, const float* __restrict__ U,
                       const float* __restrict__ x,
                       const float* __restrict__ scale, const float* __restrict__ shift,
                       float* __restrict__ out) {
    int tile = blockIdx.x, og2 = blockIdx.y, b = blockIdx.z;
    int ty0 = (tile / 6) * 32, tx0 = (tile % 6) * 32;
    __shared__ float h0[34 * 35], h1[34 * 35];
    stage_g(gmap, b, ty0, tx0, h0, h1);
    __syncthreads();

    int w = __builtin_amdgcn_readfirstlane(threadIdx.x >> 6);
    int lane = threadIdx.x & 63;
    for (int g4 = 0; g4 < 4; g4++) {
        int oc0 = (og2 * 4 + g4) * 8 + w * 2;
        float u0[2][9], u1[2][9], sc[2], sh[2];
        #pragma unroll
        for (int j = 0; j < 2; j++) {
            const float* up = U + ((b * C + oc0 + j) * 2) * 9;
            #pragma unroll
            for (int t = 0; t < 9; t++) { u0[j][t] = up[t]; u1[j][t] = up[9 + t]; }
            sc[j] = scale[oc0 + j]; sh[j] = shift[oc0 + j];
        }
        for (int it = 0; it < 4; it++) {
            int row = it * 8 + (lane >> 3);
            int c0 = (lane & 7) * 4;
            float g0v[3][6], g1v[3][6];
            #pragma unroll
            for (int dy = 0; dy < 3; dy++)
                #pragma unroll
                for (int dx = 0; dx < 6; dx++) {
                    g0v[dy][dx] = h0[(row + dy) * 35 + c0 + dx];
                    g1v[dy][dx] = h1[(row + dy) * 35 + c0 + dx];
                }
            #pragma unroll
            for (int j = 0; j < 2; j++) {
                float y4[4];
                #pragma unroll
                for (int px = 0; px < 4; px++) {
                    float y = 0.f;
                    #pragma unroll
                    for (int ky = 0; ky < 3; ky++)
                        #pragma unroll
                        for (int kx = 0; kx < 3; kx++) {
                            y += u0[j][ky * 3 + kx] * g0v[ky][px + kx];
                            y += u1[j][ky * 3 + kx] * g1v[ky][px + kx];
                        }
                    y4[px] = y;
                }
                int ga = (b * C + oc0 + j) * P + (ty0 + row) * WWD + tx0 + c0;
                float4 xv = *(const float4*)(x + ga);
                float4 ov;
                ov.x = fmaxf(y4[0] * sc[j] + sh[j], 0.f) + xv.x;
                ov.y = fmaxf(y4[1] * sc[j] + sh[j], 0.f) + xv.y;
                ov.z = fmaxf(y4[2] * sc[j] + sh[j], 0.f) + xv.z;
                ov.w = fmaxf(y4[3] * sc[j] + sh[j], 0.f) + xv.w;
                *(float4*)(out + ga) = ov;
            }
        }
    }
}

extern "C" void kernel_launch(void* const* d_in, const int* in_sizes, int n_in,
                              void* d_out, int out_size, void* d_ws, size_t ws_size,
                              hipStream_t stream) {
    const float* x     = (const float*)d_in[0];
    const float* cs    = (const float*)d_in[1];
    const float* Wc    = (const float*)d_in[2];
    const float* Wxs   = (const float*)d_in[3];
    const float* Wcsp  = (const float*)d_in[4];
    const float* Wcval = (const float*)d_in[5];
    const float* Wattn = (const float*)d_in[6];
    const float* Wcomb = (const float*)d_in[7];
    const float* Wsing = (const float*)d_in[8];
    const float* gamma = (const float*)d_in[9];
    const float* beta  = (const float*)d_in[10];
    float* ws  = (float*)d_ws;
    float* out = (float*)d_out;

    float* spp   = ws + OFF_SPACE;
    float* Wt    = ws + OFF_WT;      // overlays spp (dead after k_R2)
    float* gmap  = ws + OFF_GM;      // overlays spp (dead after k_R2)
    float* WsT   = ws + OFF_WST;     // overlays spp (dead after k_R2)
    float* Spart = ws + OFF_SPART;
    float* R     = ws + OFF_R;
    float* tok2  = ws + OFF_TOK2;
    float* U     = ws + OFF_U;
    float* STp   = ws + OFF_STP;
    float* scale = ws + OFF_SCALE;
    float* shift = ws + OFF_SHIFT;

    // zero padded-space halos + R accumulator + tok2 accumulator (contiguous range)
    hipMemsetAsync(ws, 0, (size_t)(OFF_TOK2 + 1024) * sizeof(float), stream);

    k_space<<<dim3(144, 16), 256, 0, stream>>>(cs, Wc, spp, Spart);
    k_R2   <<<dim3(96, 8), 256, 0, stream>>>(x, spp, R);
    k_wtb  <<<dim3(1296), 256, 0, stream>>>(Wxs, Wsing, Wt, WsT);  // spp dead from here
    k_g    <<<dim3(144, 16), 256, 0, stream>>>(cs, Wcval, Wattn, Wcomb, gmap);
    k_tok2 <<<dim3(16, 8, 4), 64, 0, stream>>>(Wt, Wcsp, R, Spart, tok2);
    k_U    <<<dim3(8, 2), 576, 0, stream>>>(WsT, tok2, U);
    k_cs   <<<dim3(36, 2, 8), 256, 0, stream>>>(gmap, U, STp);
    k_bnfin<<<1, 256, 0, stream>>>(STp, gamma, beta, scale, shift);
    k_fin2 <<<dim3(36, 2, 8), 256, 0, stream>>>(gmap, U, x, scale, shift, out);
}